// Round 17
// baseline (121.175 us; speedup 1.0000x reference)
//
#include <hip/hip_runtime.h>

typedef __attribute__((ext_vector_type(4))) float f32x4;
typedef __attribute__((ext_vector_type(8))) short bf16x8;

constexpr int CIN = 256;
constexpr int D   = 128;
constexpr int K   = 1024;
constexpr int HW  = 4096;    // 64*64
constexpr int MT  = 64;      // pixels per workgroup -> 1024 wgs (3/CU capacity)
constexpr int DIFF_OFF = 8388608;
constexpr int IDX_OFF  = 8388609;

// static device scratch
__device__ float g_scratch[16 + K];                       // [0]=diff acc, [16+k]=||e_k||^2
__device__ __align__(16) uint4 g_efrags[64 * 4 * 64];     // e B-frags (bf16 single) [kt][dc][lane]
__device__ __align__(16) uint4 g_wfrags[8 * 8 * 3 * 64];  // W B-frags [cb][db][s3][lane]
__device__ __align__(16) float g_embedT[K * D];           // embed transposed [K][D]

__device__ inline unsigned short f2bf(float f) {          // f32 -> bf16 RNE
    unsigned u = __float_as_uint(f);
    u = u + 0x7fff + ((u >> 16) & 1);
    return (unsigned short)(u >> 16);
}
__device__ inline float bf2f(unsigned short h) {
    return __uint_as_float(((unsigned)h) << 16);
}
// RNE triple split (used in prep for W; max accuracy)
__device__ inline void split3(float v, short& a, short& b, short& c) {
    unsigned short h = f2bf(v); float r1 = v - bf2f(h);
    unsigned short m = f2bf(r1); float r2 = r1 - bf2f(m);
    a = (short)h; b = (short)m; c = (short)f2bf(r2);
}
// truncation triple split (cheap, residual <= 2^-24 |v|; subtractions exact)
__device__ inline void split3t(float v, short& a, short& b, short& c) {
    unsigned u1 = __float_as_uint(v) & 0xffff0000u;
    float r1 = v - __uint_as_float(u1);
    unsigned u2 = __float_as_uint(r1) & 0xffff0000u;
    float r2 = r1 - __uint_as_float(u2);
    a = (short)(u1 >> 16); b = (short)(u2 >> 16);
    c = (short)(__float_as_uint(r2) >> 16);
}
// single-instruction 3-input median / min (T17: clang does NOT fuse the
// fmax/fmin idiom — R9 post-mortem, +12us VALU)
__device__ inline float med3f(float a, float b, float c) {
    float d;
    asm("v_med3_f32 %0, %1, %2, %3" : "=v"(d) : "v"(a), "v"(b), "v"(c));
    return d;
}
__device__ inline float min3f(float a, float b, float c) {
    float d;
    asm("v_min3_f32 %0, %1, %2, %3" : "=v"(d) : "v"(a), "v"(b), "v"(c));
    return d;
}
// pack k-index into low 10 mantissa bits (values guaranteed positive ->
// float compare == (quantized value, k) lexicographic)
__device__ inline float packk(float s, int kk) {
    return __uint_as_float((__float_as_uint(s) & 0xFFFFFC00u) | (unsigned)kk);
}

// async global->LDS, 16B per lane; lds dest = wave-uniform base + lane*16
__device__ inline void gload_lds16(const uint4* g, uint4* l) {
    __builtin_amdgcn_global_load_lds(
        (const __attribute__((address_space(1))) unsigned int*)g,
        (__attribute__((address_space(3))) unsigned int*)l,
        16, 0, 0);
}

// ---------------- Fused prep: transpose + e-frags + W-frags + norms --------
__global__ void vq_prep_all(const float* __restrict__ embed,
                            const float* __restrict__ conv_w) {
    const int bi = blockIdx.x;
    const int t  = threadIdx.x;
    if (bi < 128) {
        __shared__ float tile[32][33];
        int kb = bi >> 2, db = bi & 3;
        int tk = t & 31, td = t >> 5;
        #pragma unroll
        for (int dd = 0; dd < 4; ++dd)
            tile[td * 4 + dd][tk] =
                embed[(size_t)(db * 32 + td * 4 + dd) * K + kb * 32 + tk];
        __syncthreads();
        #pragma unroll
        for (int dd = 0; dd < 4; ++dd)
            g_embedT[(size_t)(kb * 32 + td * 4 + dd) * D + db * 32 + tk] =
                tile[tk][td * 4 + dd];
    } else if (bi < 192) {
        int kt = bi - 128, dc = t >> 6, l = t & 63;
        int k  = kt * 16 + (l & 15);
        int d0 = dc * 32 + (l >> 4) * 8;
        unsigned short hi[8];
        #pragma unroll
        for (int j = 0; j < 8; ++j)
            hi[j] = f2bf(embed[(size_t)(d0 + j) * K + k]);
        uint4 H;
        H.x = (unsigned)hi[0] | ((unsigned)hi[1] << 16);
        H.y = (unsigned)hi[2] | ((unsigned)hi[3] << 16);
        H.z = (unsigned)hi[4] | ((unsigned)hi[5] << 16);
        H.w = (unsigned)hi[6] | ((unsigned)hi[7] << 16);
        g_efrags[(kt * 4 + dc) * 64 + l] = H;
    } else if (bi < 208) {
        int old = (bi - 192) * 4 + (t >> 6), l = t & 63;
        int cb = old >> 3, db = old & 7;
        int c0 = cb * 32 + (l >> 4) * 8, d = db * 16 + (l & 15);
        short s1[8], s2[8], s3[8];
        #pragma unroll
        for (int j = 0; j < 8; ++j)
            split3(conv_w[(size_t)(c0 + j) * D + d], s1[j], s2[j], s3[j]);
        #pragma unroll
        for (int s = 0; s < 3; ++s) {
            const short* sp = s == 0 ? s1 : s == 1 ? s2 : s3;
            uint4 P;
            P.x = (unsigned)(unsigned short)sp[0] | ((unsigned)(unsigned short)sp[1] << 16);
            P.y = (unsigned)(unsigned short)sp[2] | ((unsigned)(unsigned short)sp[3] << 16);
            P.z = (unsigned)(unsigned short)sp[4] | ((unsigned)(unsigned short)sp[5] << 16);
            P.w = (unsigned)(unsigned short)sp[6] | ((unsigned)(unsigned short)sp[7] << 16);
            g_wfrags[((cb * 8 + db) * 3 + s) * 64 + l] = P;
        }
    } else {
        int k = (bi - 208) * 256 + t;
        if (k == 0) g_scratch[0] = 0.0f;
        float s = 0.0f;
        for (int d = 0; d < D; ++d) { float v = embed[d * K + k]; s += v * v; }
        g_scratch[16 + k] = s;
    }
}

#define MFMA(a, bb, c) __builtin_amdgcn_mfma_f32_16x16x32_bf16(a, bb, c, 0, 0, 0)

__global__ __launch_bounds__(256, 3) void vq_main(
    const float* __restrict__ x, const float* __restrict__ conv_b,
    float* __restrict__ out)
{
    // LDS slimmed for 3 blocks/CU (<=53.3KB):
    // ebuf: phase 1 = W-splits-1,2 dbuf (2x1024 uint4 = 32KB; W3 read from L2);
    //       phase 2 = e-frag dbuf (2x1024 uint4, 4-kt chunks)
    __shared__ __align__(16) uint4 ebuf[2048];      // 32768 B
    __shared__ float e2_s[K];                       // 4096 B
    __shared__ float tbuf[4 * 16 * 36];             // 9216 B per-wave transpose bounce
    __shared__ int   ks_s[MT];                      // 256 B
    __shared__ float red_s[4];
    // total ~45.3 KB -> 3 blocks/CU (12 waves)

    const int t    = threadIdx.x;
    const int lane = t & 63;
    const int w    = t >> 6;
    const int wg   = blockIdx.x;        // 0..1023
    const int n0   = wg * MT;
    const int b    = n0 >> 12;
    const int hw0  = n0 & 4095;
    const int pxb  = w * 16;            // wave's 16-pixel block
    const int lp   = lane & 15;
    const int lg   = lane >> 4;
    const float INF = __uint_as_float(0x7f800000u);

    for (int k = t; k < K; k += 256) e2_s[k] = g_scratch[16 + k];

    // -------- Phase 1: z = x^T W + bias via MFMA, TRIPLE split (6 products) -----
    // (rule #20: all indices compile-time after unroll. W1,W2 from LDS dbuf;
    //  W3 [used 1/6 products] direct from L2 with register prefetch chain.)
    f32x4 Cz[8];                        // C tiles [db]: row px (16), col d
    #pragma unroll
    for (int db = 0; db < 8; ++db) {
        float bv = conv_b[db * 16 + lp];
        Cz[db] = (f32x4){bv, bv, bv, bv};
    }
    {
        // prologue: DMA-stage W12 chunk cb=0 (16 blocks of 64 uint4; wave does 4)
        #pragma unroll
        for (int ii = 0; ii < 4; ++ii) {
            int bi = w * 4 + ii;        // db = bi>>1, s = bi&1
            gload_lds16(&g_wfrags[(((bi >> 1)) * 3 + (bi & 1)) * 64 + lane],
                        &ebuf[bi * 64]);
        }
        asm volatile("s_waitcnt vmcnt(0)" ::: "memory");
        __syncthreads();

        const float* xl = x + (size_t)b * CIN * HW + (size_t)(lg * 8) * HW
                          + hw0 + pxb + lp;
        for (int cb = 0; cb < 8; ++cb) {
            // x loads FIRST (consumed this iteration)
            float v[8];
            #pragma unroll
            for (int j = 0; j < 8; ++j)
                v[j] = xl[(size_t)(cb * 32 + j) * HW];
            if (cb < 7) {
                #pragma unroll
                for (int ii = 0; ii < 4; ++ii) {
                    int bi = w * 4 + ii;
                    gload_lds16(&g_wfrags[(((cb + 1) * 8 + (bi >> 1)) * 3 + (bi & 1)) * 64 + lane],
                                &ebuf[((cb + 1) & 1) * 1024 + bi * 64]);
                }
            }
            bf16x8 X1, X2, X3;
            #pragma unroll
            for (int j = 0; j < 8; ++j) {
                short a, bb, c;
                split3t(v[j], a, bb, c);
                X1[j] = a; X2[j] = bb; X3[j] = c;
            }
            const uint4* wb = ebuf + (cb & 1) * 1024;
            // W3 register prefetch chain (L2-resident)
            bf16x8 W3n = *(const bf16x8*)&g_wfrags[((cb * 8 + 0) * 3 + 2) * 64 + lane];
            #pragma unroll
            for (int db = 0; db < 8; ++db) {
                bf16x8 W3 = W3n;
                if (db < 7)
                    W3n = *(const bf16x8*)&g_wfrags[((cb * 8 + db + 1) * 3 + 2) * 64 + lane];
                bf16x8 W1 = *(const bf16x8*)&wb[(db * 2 + 0) * 64 + lane];
                bf16x8 W2 = *(const bf16x8*)&wb[(db * 2 + 1) * 64 + lane];
                Cz[db] = MFMA(X1, W1, Cz[db]);
                Cz[db] = MFMA(X1, W2, Cz[db]);
                Cz[db] = MFMA(X2, W1, Cz[db]);
                Cz[db] = MFMA(X1, W3, Cz[db]);
                Cz[db] = MFMA(X2, W2, Cz[db]);
                Cz[db] = MFMA(X3, W1, Cz[db]);
            }
            asm volatile("s_waitcnt vmcnt(0)" ::: "memory");
            __syncthreads();
        }
    }

    // ------------- Transpose C-layout -> phase-2 A-frags (bf16 single) -----
    // A-frag: lane holds -2z[px = lp][d = dc*32 + lg*8 + j]
    bf16x8 A2h[4];
    {
        float* tb = tbuf + w * 576;         // [16][36] per wave (wave-local sync only)
        #pragma unroll
        for (int dc = 0; dc < 4; ++dc) {
            #pragma unroll
            for (int h = 0; h < 2; ++h)
                #pragma unroll
                for (int r = 0; r < 4; ++r)
                    tb[(lg * 4 + r) * 36 + h * 16 + lp] = Cz[dc * 2 + h][r];
            asm volatile("s_waitcnt lgkmcnt(0)" ::: "memory");
            f32x4 a0 = *(const f32x4*)&tb[lp * 36 + lg * 8];
            f32x4 a1 = *(const f32x4*)&tb[lp * 36 + lg * 8 + 4];
            #pragma unroll
            for (int j = 0; j < 8; ++j)
                A2h[dc][j] = (short)f2bf(-2.0f * (j < 4 ? a0[j] : a1[j - 4]));
            asm volatile("s_waitcnt lgkmcnt(0)" ::: "memory");
        }
    }

    // ------- Phase 2: bf16-single MFMA + packed top-4/lane tracking --------
    // s = e2 + 512 - 2z.e (offset => s > 0: float-bit order valid).
    // 16 chunks of 4 kt (16KB), double-buffered, R14 drain pattern.
    const uint4* gfr = g_efrags;
    {   // DMA-stage chunk 0
        #pragma unroll
        for (int i = 0; i < 4; ++i)
            gload_lds16(&gfr[w * 256 + i * 64 + lane], &ebuf[w * 256 + i * 64]);
        asm volatile("s_waitcnt vmcnt(0)" ::: "memory");
        __syncthreads();
    }

    float v1[4], v2[4], v3[4], v4[4];       // per-q sorted packed top-4
    #pragma unroll
    for (int q = 0; q < 4; ++q) { v1[q] = INF; v2[q] = INF; v3[q] = INF; v4[q] = INF; }

    for (int c = 0; c < 16; ++c) {
        if (c < 15) {                       // issue next-chunk DMA before compute
            const uint4* esrc = gfr + (size_t)(c + 1) * 1024;
            uint4* edst = ebuf + ((c + 1) & 1) * 1024;
            #pragma unroll
            for (int i = 0; i < 4; ++i)
                gload_lds16(&esrc[w * 256 + i * 64 + lane], &edst[w * 256 + i * 64]);
        }
        const bf16x8* eb = (const bf16x8*)&ebuf[(c & 1) * 1024];
        #pragma unroll
        for (int ktl = 0; ktl < 4; ++ktl) {
            int kt = c * 4 + ktl;
            bf16x8 Bh[4];
            #pragma unroll
            for (int dc = 0; dc < 4; ++dc)
                Bh[dc] = eb[(ktl * 4 + dc) * 64 + lane];
            float e2v = e2_s[kt * 16 + lp] + 512.0f;
            f32x4 C0 = (f32x4){e2v, e2v, e2v, e2v};
            __builtin_amdgcn_s_setprio(1);
            #pragma unroll
            for (int dc = 0; dc < 4; ++dc)
                C0 = MFMA(A2h[dc], Bh[dc], C0);
            __builtin_amdgcn_s_setprio(0);
            int kk = kt * 16 + lp;
            #pragma unroll
            for (int q = 0; q < 4; ++q) {
                float s = packk(C0[q], kk);
                float t1 = fminf(v1[q], s);
                float t2 = med3f(s, v1[q], v2[q]);
                float t3 = med3f(s, v2[q], v3[q]);
                float t4 = med3f(s, v3[q], v4[q]);
                v1[q] = t1; v2[q] = t2; v3[q] = t3; v4[q] = t4;
            }
        }
        if (c < 15) {
            asm volatile("s_waitcnt vmcnt(0)" ::: "memory");
            __syncthreads();
        }
    }

    // ---- Per q: 16-lane merge to global top-6, exact f32 refine, diff -----
    // (xor offsets 1..8 stay within the 16-lane group; each lg-group handles
    //  its own 4 pixels px = pxb + lg*4 + q)
    float dacc = 0.0f;
    #pragma unroll
    for (int q = 0; q < 4; ++q) {
        float a1 = v1[q], a2 = v2[q], a3 = v3[q], a4 = v4[q], a5 = INF, a6 = INF;
        // butterfly merge of sorted-6 lists: c_i = min_{j} max(a_j, b_{i-j})
        #pragma unroll
        for (int off = 1; off < 16; off <<= 1) {
            float b1 = __shfl_xor(a1, off), b2 = __shfl_xor(a2, off);
            float b3 = __shfl_xor(a3, off), b4 = __shfl_xor(a4, off);
            float b5 = __shfl_xor(a5, off), b6 = __shfl_xor(a6, off);
            float m11 = fmaxf(a1, b1);
            float m12 = fmaxf(a1, b2), m21 = fmaxf(a2, b1);
            float m13 = fmaxf(a1, b3), m22 = fmaxf(a2, b2), m31 = fmaxf(a3, b1);
            float m14 = fmaxf(a1, b4), m23 = fmaxf(a2, b3), m32 = fmaxf(a3, b2), m41 = fmaxf(a4, b1);
            float m15 = fmaxf(a1, b5), m24 = fmaxf(a2, b4), m33 = fmaxf(a3, b3), m42 = fmaxf(a4, b2), m51 = fmaxf(a5, b1);
            float c1 = fminf(a1, b1);
            float c2 = min3f(a2, b2, m11);
            float c3 = min3f(m12, m21, fminf(a3, b3));
            float c4 = fminf(min3f(a4, b4, m13), fminf(m22, m31));
            float c5 = fminf(min3f(a5, b5, m14), min3f(m23, m32, m41));
            float c6 = fminf(fminf(min3f(a6, b6, m15), min3f(m24, m33, m42)), m51);
            a1 = c1; a2 = c2; a3 = c3; a4 = c4; a5 = c5; a6 = c6;
        }
        float cm[6] = {a1, a2, a3, a4, a5, a6};
        float bd = 0.0f; int bk = 0;
        #pragma unroll
        for (int j = 0; j < 6; ++j) {
            int kc = (int)(__float_as_uint(cm[j]) & 1023u);
            float sum = 0.0f;
            #pragma unroll
            for (int db = 0; db < 8; ++db)
                sum += Cz[db][q] * g_embedT[(size_t)kc * D + db * 16 + lp];
            #pragma unroll
            for (int off = 1; off < 16; off <<= 1) sum += __shfl_xor(sum, off);
            float de = e2_s[kc] - 2.0f * sum;
            if (j == 0) { bd = de; bk = kc; }
            else {
                bool upd = (de < bd) || (de == bd && kc < bk);
                bd = upd ? de : bd;
                bk = upd ? kc : bk;
            }
        }
        #pragma unroll
        for (int db = 0; db < 8; ++db) {
            float qv = g_embedT[(size_t)bk * D + db * 16 + lp];
            float df = qv - Cz[db][q];
            dacc += df * df;
        }
        if (lp == 0) {
            int px = pxb + lg * 4 + q;
            ks_s[px] = bk;
            out[IDX_OFF + n0 + px] = (float)bk;
        }
    }
    #pragma unroll
    for (int off = 1; off <= 32; off <<= 1) dacc += __shfl_xor(dacc, off);
    if (lane == 0) red_s[w] = dacc;
    __syncthreads();

    // ---------------- Epilogue: gather quantize, transpose-write -----------
    {
        int px = t & 63, quarter = t >> 6;       // 4 d-groups of 32
        int ks = ks_s[px];
        const f32x4* ep = (const f32x4*)&g_embedT[(size_t)ks * D + quarter * 32];
        float* ob = out + (size_t)b * D * HW + hw0 + px;
        #pragma unroll
        for (int d4 = 0; d4 < 8; ++d4) {
            f32x4 q4 = ep[d4];
            int d = quarter * 32 + d4 * 4;
            #pragma unroll
            for (int cc = 0; cc < 4; ++cc)
                ob[(size_t)(d + cc) * HW] = q4[cc];
        }
    }
    if (t == 0) atomicAdd(&g_scratch[0], red_s[0] + red_s[1] + red_s[2] + red_s[3]);
}

__global__ void vq_final(float* __restrict__ out) {
    out[DIFF_OFF] = g_scratch[0] / 8388608.0f;
}

extern "C" void kernel_launch(void* const* d_in, const int* in_sizes, int n_in,
                              void* d_out, int out_size, void* d_ws, size_t ws_size,
                              hipStream_t stream) {
    const float* x      = (const float*)d_in[0];
    const float* conv_w = (const float*)d_in[1];
    const float* conv_b = (const float*)d_in[2];
    const float* embed  = (const float*)d_in[3];
    float* out = (float*)d_out;

    vq_prep_all<<<212,  256, 0, stream>>>(embed, conv_w);
    vq_main    <<<1024, 256, 0, stream>>>(x, conv_b, out);
    vq_final   <<<1,    1,   0, stream>>>(out);
}

// Round 18
// 84.846 us; speedup vs baseline: 1.4282x; 1.4282x over previous
//
#include <hip/hip_runtime.h>

typedef __attribute__((ext_vector_type(4))) float f32x4;
typedef __attribute__((ext_vector_type(8))) short bf16x8;

constexpr int CIN = 256;
constexpr int D   = 128;
constexpr int K   = 1024;
constexpr int HW  = 4096;    // 64*64
constexpr int MT  = 128;     // pixels per workgroup -> 512 wgs (2/CU)
constexpr int DIFF_OFF = 8388608;
constexpr int IDX_OFF  = 8388609;

// static device scratch
__device__ float g_scratch[16 + K];                       // [0]=diff acc, [16+k]=||e_k||^2
__device__ __align__(16) uint4 g_efrags[64 * 4 * 64];     // e B-frags (bf16 single) [kt][dc][lane]
__device__ __align__(16) uint4 g_wfrags[8 * 8 * 3 * 64];  // W B-frags [cb][db][s3][lane]
__device__ __align__(16) float g_embedT[K * D];           // embed transposed [K][D]

__device__ inline unsigned short f2bf(float f) {          // f32 -> bf16 RNE
    unsigned u = __float_as_uint(f);
    u = u + 0x7fff + ((u >> 16) & 1);
    return (unsigned short)(u >> 16);
}
__device__ inline float bf2f(unsigned short h) {
    return __uint_as_float(((unsigned)h) << 16);
}
// RNE triple split (used in prep for W; max accuracy)
__device__ inline void split3(float v, short& a, short& b, short& c) {
    unsigned short h = f2bf(v); float r1 = v - bf2f(h);
    unsigned short m = f2bf(r1); float r2 = r1 - bf2f(m);
    a = (short)h; b = (short)m; c = (short)f2bf(r2);
}
// truncation triple split (cheap, residual <= 2^-24 |v|; subtractions exact)
__device__ inline void split3t(float v, short& a, short& b, short& c) {
    unsigned u1 = __float_as_uint(v) & 0xffff0000u;
    float r1 = v - __uint_as_float(u1);
    unsigned u2 = __float_as_uint(r1) & 0xffff0000u;
    float r2 = r1 - __uint_as_float(u2);
    a = (short)(u1 >> 16); b = (short)(u2 >> 16);
    c = (short)(__float_as_uint(r2) >> 16);
}
// single-instruction 3-input median / min (T17: clang does NOT fuse the
// fmax/fmin idiom — R9 post-mortem, +12us VALU)
__device__ inline float med3f(float a, float b, float c) {
    float d;
    asm("v_med3_f32 %0, %1, %2, %3" : "=v"(d) : "v"(a), "v"(b), "v"(c));
    return d;
}
__device__ inline float min3f(float a, float b, float c) {
    float d;
    asm("v_min3_f32 %0, %1, %2, %3" : "=v"(d) : "v"(a), "v"(b), "v"(c));
    return d;
}
// pack k-index into low 10 mantissa bits (values guaranteed positive ->
// float compare == (quantized value, k) lexicographic)
__device__ inline float packk(float s, int kk) {
    return __uint_as_float((__float_as_uint(s) & 0xFFFFFC00u) | (unsigned)kk);
}

// async global->LDS, 16B per lane; lds dest = wave-uniform base + lane*16
__device__ inline void gload_lds16(const uint4* g, uint4* l) {
    __builtin_amdgcn_global_load_lds(
        (const __attribute__((address_space(1))) unsigned int*)g,
        (__attribute__((address_space(3))) unsigned int*)l,
        16, 0, 0);
}

// ---------------- Fused prep: transpose + e-frags + W-frags + norms --------
__global__ void vq_prep_all(const float* __restrict__ embed,
                            const float* __restrict__ conv_w) {
    const int bi = blockIdx.x;
    const int t  = threadIdx.x;
    if (bi < 128) {
        __shared__ float tile[32][33];
        int kb = bi >> 2, db = bi & 3;
        int tk = t & 31, td = t >> 5;
        #pragma unroll
        for (int dd = 0; dd < 4; ++dd)
            tile[td * 4 + dd][tk] =
                embed[(size_t)(db * 32 + td * 4 + dd) * K + kb * 32 + tk];
        __syncthreads();
        #pragma unroll
        for (int dd = 0; dd < 4; ++dd)
            g_embedT[(size_t)(kb * 32 + td * 4 + dd) * D + db * 32 + tk] =
                tile[tk][td * 4 + dd];
    } else if (bi < 192) {
        int kt = bi - 128, dc = t >> 6, l = t & 63;
        int k  = kt * 16 + (l & 15);
        int d0 = dc * 32 + (l >> 4) * 8;
        unsigned short hi[8];
        #pragma unroll
        for (int j = 0; j < 8; ++j)
            hi[j] = f2bf(embed[(size_t)(d0 + j) * K + k]);
        uint4 H;
        H.x = (unsigned)hi[0] | ((unsigned)hi[1] << 16);
        H.y = (unsigned)hi[2] | ((unsigned)hi[3] << 16);
        H.z = (unsigned)hi[4] | ((unsigned)hi[5] << 16);
        H.w = (unsigned)hi[6] | ((unsigned)hi[7] << 16);
        g_efrags[(kt * 4 + dc) * 64 + l] = H;
    } else if (bi < 208) {
        int old = (bi - 192) * 4 + (t >> 6), l = t & 63;
        int cb = old >> 3, db = old & 7;
        int c0 = cb * 32 + (l >> 4) * 8, d = db * 16 + (l & 15);
        short s1[8], s2[8], s3[8];
        #pragma unroll
        for (int j = 0; j < 8; ++j)
            split3(conv_w[(size_t)(c0 + j) * D + d], s1[j], s2[j], s3[j]);
        #pragma unroll
        for (int s = 0; s < 3; ++s) {
            const short* sp = s == 0 ? s1 : s == 1 ? s2 : s3;
            uint4 P;
            P.x = (unsigned)(unsigned short)sp[0] | ((unsigned)(unsigned short)sp[1] << 16);
            P.y = (unsigned)(unsigned short)sp[2] | ((unsigned)(unsigned short)sp[3] << 16);
            P.z = (unsigned)(unsigned short)sp[4] | ((unsigned)(unsigned short)sp[5] << 16);
            P.w = (unsigned)(unsigned short)sp[6] | ((unsigned)(unsigned short)sp[7] << 16);
            g_wfrags[((cb * 8 + db) * 3 + s) * 64 + l] = P;
        }
    } else {
        int k = (bi - 208) * 256 + t;
        if (k == 0) g_scratch[0] = 0.0f;
        float s = 0.0f;
        for (int d = 0; d < D; ++d) { float v = embed[d * K + k]; s += v * v; }
        g_scratch[16 + k] = s;
    }
}

#define MFMA(a, bb, c) __builtin_amdgcn_mfma_f32_16x16x32_bf16(a, bb, c, 0, 0, 0)

__global__ __launch_bounds__(256, 2) void vq_main(
    const float* __restrict__ x, const float* __restrict__ conv_b,
    float* __restrict__ out)
{
    // ebuf: phase 1 = W-frag double buffer (2x1536 uint4); phase 2 = e-frag dbuf (2x2048)
    __shared__ __align__(16) uint4 ebuf[4096];      // 65536 B
    __shared__ float e2_s[K];                       // 4096 B
    __shared__ float tbuf[4 * 16 * 36];             // 9216 B per-wave transpose bounce
    __shared__ int   ks_s[MT];
    __shared__ float red_s[4];

    const int t    = threadIdx.x;
    const int lane = t & 63;
    const int w    = t >> 6;
    const int wg   = blockIdx.x;
    const int n0   = wg * MT;
    const int b    = n0 >> 12;
    const int hw0  = n0 & 4095;
    const int pxb  = w * 32;
    const int lp   = lane & 15;
    const int lg   = lane >> 4;
    const float INF = __uint_as_float(0x7f800000u);

    for (int k = t; k < K; k += 256) e2_s[k] = g_scratch[16 + k];

    // -------- Phase 1: z = x^T W + bias via MFMA, TRIPLE split (6 products) -----
    // (R14 proven optimum: R11-R13, R15-R17 perturbations all regressed.)
    f32x4 Cz[2][8];                         // C tiles [rb][db]: row px, col d
    #pragma unroll
    for (int db = 0; db < 8; ++db) {
        float bv = conv_b[db * 16 + lp];
        Cz[0][db] = (f32x4){bv, bv, bv, bv};
        Cz[1][db] = Cz[0][db];
    }
    {
        // prologue: DMA-stage W chunk cb=0 into ebuf[0..1535]
        #pragma unroll
        for (int i = 0; i < 6; ++i)
            gload_lds16(&g_wfrags[(w * 6 + i) * 64 + lane], &ebuf[(w * 6 + i) * 64]);
        asm volatile("s_waitcnt vmcnt(0)" ::: "memory");
        __syncthreads();

        const float* xl = x + (size_t)b * CIN * HW + (size_t)(lg * 8) * HW
                          + hw0 + pxb + lp;
        for (int cb = 0; cb < 8; ++cb) {
            // x loads FIRST (consumed this iteration; compiler's counted wait
            // leaves the W-DMA below in flight)
            float v[2][8];
            #pragma unroll
            for (int rb = 0; rb < 2; ++rb)
                #pragma unroll
                for (int j = 0; j < 8; ++j)
                    v[rb][j] = xl[(size_t)(cb * 32 + j) * HW + rb * 16];
            if (cb < 7) {
                const uint4* wsrc = g_wfrags + (size_t)(cb + 1) * 1536;
                uint4* wdst = ebuf + ((cb + 1) & 1) * 1536;
                #pragma unroll
                for (int i = 0; i < 6; ++i)
                    gload_lds16(&wsrc[(w * 6 + i) * 64 + lane], &wdst[(w * 6 + i) * 64]);
            }
            bf16x8 X1[2], X2[2], X3[2];
            #pragma unroll
            for (int rb = 0; rb < 2; ++rb)
                #pragma unroll
                for (int j = 0; j < 8; ++j) {
                    short a, bb, c;
                    split3t(v[rb][j], a, bb, c);
                    X1[rb][j] = a; X2[rb][j] = bb; X3[rb][j] = c;
                }
            const uint4* wb = ebuf + (cb & 1) * 1536;
            #pragma unroll
            for (int db = 0; db < 8; ++db) {
                bf16x8 W1 = *(const bf16x8*)&wb[(db * 3 + 0) * 64 + lane];
                bf16x8 W2 = *(const bf16x8*)&wb[(db * 3 + 1) * 64 + lane];
                bf16x8 W3 = *(const bf16x8*)&wb[(db * 3 + 2) * 64 + lane];
                Cz[0][db] = MFMA(X1[0], W1, Cz[0][db]);
                Cz[1][db] = MFMA(X1[1], W1, Cz[1][db]);
                Cz[0][db] = MFMA(X1[0], W2, Cz[0][db]);
                Cz[1][db] = MFMA(X1[1], W2, Cz[1][db]);
                Cz[0][db] = MFMA(X2[0], W1, Cz[0][db]);
                Cz[1][db] = MFMA(X2[1], W1, Cz[1][db]);
                Cz[0][db] = MFMA(X1[0], W3, Cz[0][db]);
                Cz[1][db] = MFMA(X1[1], W3, Cz[1][db]);
                Cz[0][db] = MFMA(X2[0], W2, Cz[0][db]);
                Cz[1][db] = MFMA(X2[1], W2, Cz[1][db]);
                Cz[0][db] = MFMA(X3[0], W1, Cz[0][db]);
                Cz[1][db] = MFMA(X3[1], W1, Cz[1][db]);
            }
            asm volatile("s_waitcnt vmcnt(0)" ::: "memory");
            __syncthreads();
        }
    }

    // ------------- Transpose C-layout -> phase-2 A-frags (bf16 single) -----
    bf16x8 A2h[2][4];
    {
        float* tb = tbuf + w * 576;         // [16][36] per wave (wave-local sync only)
        #pragma unroll
        for (int rb = 0; rb < 2; ++rb) {
            #pragma unroll
            for (int dc = 0; dc < 4; ++dc) {
                #pragma unroll
                for (int h = 0; h < 2; ++h)
                    #pragma unroll
                    for (int r = 0; r < 4; ++r)
                        tb[(lg * 4 + r) * 36 + h * 16 + lp] = Cz[rb][dc * 2 + h][r];
                asm volatile("s_waitcnt lgkmcnt(0)" ::: "memory");
                f32x4 a0 = *(const f32x4*)&tb[lp * 36 + lg * 8];
                f32x4 a1 = *(const f32x4*)&tb[lp * 36 + lg * 8 + 4];
                #pragma unroll
                for (int j = 0; j < 8; ++j)
                    A2h[rb][dc][j] = (short)f2bf(-2.0f * (j < 4 ? a0[j] : a1[j - 4]));
                asm volatile("s_waitcnt lgkmcnt(0)" ::: "memory");
            }
        }
    }

    // ------- Phase 2: bf16-single MFMA + packed top-4/lane tracking --------
    // s = e2 + 512 - 2z.e  (offset => s > 0: float-bit order valid)
    const uint4* gfr = g_efrags;
    {   // DMA-stage chunk 0 (8 kt = 2048 uint4 = 32 KB)
        #pragma unroll
        for (int i = 0; i < 8; ++i)
            gload_lds16(&gfr[(w * 8 + i) * 64 + lane], &ebuf[(w * 8 + i) * 64]);
        asm volatile("s_waitcnt vmcnt(0)" ::: "memory");
        __syncthreads();
    }

    float v1[8], v2[8], v3[8], v4[8];       // per-q sorted packed top-4
    #pragma unroll
    for (int q = 0; q < 8; ++q) { v1[q] = INF; v2[q] = INF; v3[q] = INF; v4[q] = INF; }

    for (int c = 0; c < 8; ++c) {
        if (c < 7) {                        // issue next-chunk DMA before compute
            const uint4* esrc = gfr + (size_t)(c + 1) * 2048;
            uint4* edst = ebuf + ((c + 1) & 1) * 2048;
            #pragma unroll
            for (int i = 0; i < 8; ++i)
                gload_lds16(&esrc[(w * 8 + i) * 64 + lane], &edst[(w * 8 + i) * 64]);
        }
        const bf16x8* eb = (const bf16x8*)&ebuf[(c & 1) * 2048];
        #pragma unroll
        for (int ktl = 0; ktl < 8; ++ktl) {
            int kt = c * 8 + ktl;
            bf16x8 Bh[4];
            #pragma unroll
            for (int dc = 0; dc < 4; ++dc)
                Bh[dc] = eb[(ktl * 4 + dc) * 64 + lane];
            float e2v = e2_s[kt * 16 + lp] + 512.0f;
            f32x4 C0 = (f32x4){e2v, e2v, e2v, e2v};
            f32x4 C1 = C0;
            __builtin_amdgcn_s_setprio(1);
            #pragma unroll
            for (int dc = 0; dc < 4; ++dc) {
                C0 = MFMA(A2h[0][dc], Bh[dc], C0);
                C1 = MFMA(A2h[1][dc], Bh[dc], C1);
            }
            __builtin_amdgcn_s_setprio(0);
            int kk = kt * 16 + lp;
            #pragma unroll
            for (int rb = 0; rb < 2; ++rb) {
                f32x4 C = rb ? C1 : C0;
                #pragma unroll
                for (int r = 0; r < 4; ++r) {
                    int q = rb * 4 + r;
                    float s = packk(C[r], kk);
                    float t1 = fminf(v1[q], s);
                    float t2 = med3f(s, v1[q], v2[q]);
                    float t3 = med3f(s, v2[q], v3[q]);
                    float t4 = med3f(s, v3[q], v4[q]);
                    v1[q] = t1; v2[q] = t2; v3[q] = t3; v4[q] = t4;
                }
            }
        }
        if (c < 7) {                        // last chunk: barrier protects nothing
            asm volatile("s_waitcnt vmcnt(0)" ::: "memory");
            __syncthreads();
        }
    }

    // ---- Per q: 16-lane merge to global top-6, exact f32 refine, diff -----
    float dacc = 0.0f;
    #pragma unroll
    for (int q = 0; q < 8; ++q) {
        const int rb = q >> 2, r = q & 3;
        float a1 = v1[q], a2 = v2[q], a3 = v3[q], a4 = v4[q], a5 = INF, a6 = INF;
        // butterfly merge of sorted-6 lists: c_i = min_{j} max(a_j, b_{i-j})
        #pragma unroll
        for (int off = 1; off < 16; off <<= 1) {
            float b1 = __shfl_xor(a1, off), b2 = __shfl_xor(a2, off);
            float b3 = __shfl_xor(a3, off), b4 = __shfl_xor(a4, off);
            float b5 = __shfl_xor(a5, off), b6 = __shfl_xor(a6, off);
            float m11 = fmaxf(a1, b1);
            float m12 = fmaxf(a1, b2), m21 = fmaxf(a2, b1);
            float m13 = fmaxf(a1, b3), m22 = fmaxf(a2, b2), m31 = fmaxf(a3, b1);
            float m14 = fmaxf(a1, b4), m23 = fmaxf(a2, b3), m32 = fmaxf(a3, b2), m41 = fmaxf(a4, b1);
            float m15 = fmaxf(a1, b5), m24 = fmaxf(a2, b4), m33 = fmaxf(a3, b3), m42 = fmaxf(a4, b2), m51 = fmaxf(a5, b1);
            float c1 = fminf(a1, b1);
            float c2 = min3f(a2, b2, m11);
            float c3 = min3f(m12, m21, fminf(a3, b3));
            float c4 = fminf(min3f(a4, b4, m13), fminf(m22, m31));
            float c5 = fminf(min3f(a5, b5, m14), min3f(m23, m32, m41));
            float c6 = fminf(fminf(min3f(a6, b6, m15), min3f(m24, m33, m42)), m51);
            a1 = c1; a2 = c2; a3 = c3; a4 = c4; a5 = c5; a6 = c6;
        }
        float cm[6] = {a1, a2, a3, a4, a5, a6};
        float bd = 0.0f; int bk = 0;
        #pragma unroll
        for (int j = 0; j < 6; ++j) {
            int kc = (int)(__float_as_uint(cm[j]) & 1023u);
            float sum = 0.0f;
            #pragma unroll
            for (int db = 0; db < 8; ++db)
                sum += Cz[rb][db][r] * g_embedT[(size_t)kc * D + db * 16 + lp];
            #pragma unroll
            for (int off = 1; off < 16; off <<= 1) sum += __shfl_xor(sum, off);
            float de = e2_s[kc] - 2.0f * sum;
            if (j == 0) { bd = de; bk = kc; }
            else {
                bool upd = (de < bd) || (de == bd && kc < bk);
                bd = upd ? de : bd;
                bk = upd ? kc : bk;
            }
        }
        #pragma unroll
        for (int db = 0; db < 8; ++db) {
            float qv = g_embedT[(size_t)bk * D + db * 16 + lp];
            float df = qv - Cz[rb][db][r];
            dacc += df * df;
        }
        if (lp == 0) {
            int px = pxb + rb * 16 + lg * 4 + r;
            ks_s[px] = bk;
            out[IDX_OFF + n0 + px] = (float)bk;
        }
    }
    #pragma unroll
    for (int off = 1; off <= 32; off <<= 1) dacc += __shfl_xor(dacc, off);
    if (lane == 0) red_s[w] = dacc;
    __syncthreads();

    // ---------------- Epilogue: gather quantize, transpose-write -----------
    {
        int px = t & 127, half = t >> 7;
        int ks = ks_s[px];
        const f32x4* ep = (const f32x4*)&g_embedT[(size_t)ks * D + half * 64];
        float* ob = out + (size_t)b * D * HW + hw0 + px;
        #pragma unroll
        for (int d4 = 0; d4 < 16; ++d4) {
            f32x4 q4 = ep[d4];
            int d = half * 64 + d4 * 4;
            #pragma unroll
            for (int cc = 0; cc < 4; ++cc)
                ob[(size_t)(d + cc) * HW] = q4[cc];
        }
    }
    if (t == 0) atomicAdd(&g_scratch[0], red_s[0] + red_s[1] + red_s[2] + red_s[3]);
}

__global__ void vq_final(float* __restrict__ out) {
    out[DIFF_OFF] = g_scratch[0] / 8388608.0f;
}

extern "C" void kernel_launch(void* const* d_in, const int* in_sizes, int n_in,
                              void* d_out, int out_size, void* d_ws, size_t ws_size,
                              hipStream_t stream) {
    const float* x      = (const float*)d_in[0];
    const float* conv_w = (const float*)d_in[1];
    const float* conv_b = (const float*)d_in[2];
    const float* embed  = (const float*)d_in[3];
    float* out = (float*)d_out;

    vq_prep_all<<<212, 256, 0, stream>>>(embed, conv_w);
    vq_main    <<<512, 256, 0, stream>>>(x, conv_b, out);
    vq_final   <<<1,   1,   0, stream>>>(out);
}